// Round 2
// baseline (1263.884 us; speedup 1.0000x reference)
//
#include <hip/hip_runtime.h>

#define NN 50000
#define NE 400000
#define DH 128
#define NHEAD 8
#define RB 16
#define AP 20   // padded pitch (floats) for transposed LDS tiles; 80B rows keep 16B align

typedef unsigned int u32;
typedef unsigned short u16;

__device__ __forceinline__ float bflo(u32 w){ union{u32 i; float f;} v; v.i = w<<16; return v.f; }
__device__ __forceinline__ float bfhi(u32 w){ union{u32 i; float f;} v; v.i = w & 0xffff0000u; return v.f; }
__device__ __forceinline__ u32 packbf(float a, float b){
  union{float f;u32 i;} x, y; x.f=a; y.f=b;
  u32 xi = x.i + (((x.i>>16)&1u) + 0x7fffu);
  u32 yi = y.i + (((y.i>>16)&1u) + 0x7fffu);
  return (xi>>16) | (yi & 0xffff0000u);
}

__device__ __forceinline__ float wred64(float v){
  #pragma unroll
  for (int o=32;o;o>>=1) v += __shfl_xor(v, o);
  return v;
}

// A-tile transposed in LDS: at[k][row], pitch AP. Lane owns output cols (colbase+2l, +1).
template<int K, int STRIDE>
__device__ __forceinline__ void gemm2(const float (*at)[AP], const float* __restrict__ W,
                                      int colbase, int l, float acc0[RB], float acc1[RB])
{
  const int c = colbase + 2*l;
  for (int r=0; r<K; ++r) {
    float2 w = *(const float2*)(W + (size_t)r*STRIDE + c);
    const float4* ar = (const float4*)&at[r][0];
    #pragma unroll
    for (int q=0;q<RB/4;++q){
      float4 av = ar[q];
      acc0[4*q+0] += av.x*w.x; acc1[4*q+0] += av.x*w.y;
      acc0[4*q+1] += av.y*w.x; acc1[4*q+1] += av.y*w.y;
      acc0[4*q+2] += av.z*w.x; acc1[4*q+2] += av.z*w.y;
      acc0[4*q+3] += av.w*w.x; acc1[4*q+3] += av.w*w.y;
    }
  }
}

// LayerNorm RB rows of src into transposed LDS tile; optionally save raw vals for residual
template<bool SAVE>
__device__ __forceinline__ void ln_rows(const float* __restrict__ src, int base, int l,
                                        float g0, float g1, float bb0, float bb1,
                                        float (*at)[AP], float* r0, float* r1)
{
  for (int e=0;e<RB;++e){
    float2 x = *(const float2*)(src + (size_t)(base+e)*DH + 2*l);
    if (SAVE){ r0[e]=x.x; r1[e]=x.y; }
    float s  = wred64(x.x+x.y);
    float s2 = wred64(x.x*x.x+x.y*x.y);
    float mu = s*(1.0f/DH);
    float var = fmaxf(s2*(1.0f/DH) - mu*mu, 0.f);
    float rs = rsqrtf(var + 1e-5f);
    at[2*l][e]   = (x.x-mu)*rs*g0 + bb0;
    at[2*l+1][e] = (x.y-mu)*rs*g1 + bb1;
  }
}

// ---------------- K1: node LN + q,k,v projections (stored bf16-packed) ----------------
__global__ __launch_bounds__(64)
void k_qkv(const float* __restrict__ xin,
           const float* __restrict__ Wq, const float* __restrict__ bq,
           const float* __restrict__ Wk, const float* __restrict__ bk,
           const float* __restrict__ Wv, const float* __restrict__ bv,
           const float* __restrict__ lg, const float* __restrict__ lb,
           u32* __restrict__ qo, u32* __restrict__ ko, u32* __restrict__ vo)
{
  __shared__ __align__(16) float at[DH][AP];
  const int l = threadIdx.x;
  const int base = blockIdx.x * RB;
  float2 g = *(const float2*)(lg + 2*l);
  float2 b = *(const float2*)(lb + 2*l);
  ln_rows<false>(xin, base, l, g.x, g.y, b.x, b.y, at, nullptr, nullptr);
  __syncthreads();

  float a0[RB], a1[RB];
  // Q
  #pragma unroll
  for(int e=0;e<RB;++e){a0[e]=0.f;a1[e]=0.f;}
  gemm2<DH,DH>(at, Wq, 0, l, a0, a1);
  { float2 bb=*(const float2*)(bq+2*l);
    #pragma unroll
    for(int e=0;e<RB;++e) qo[(size_t)(base+e)*64 + l] = packbf(a0[e]+bb.x, a1[e]+bb.y); }
  // K
  #pragma unroll
  for(int e=0;e<RB;++e){a0[e]=0.f;a1[e]=0.f;}
  gemm2<DH,DH>(at, Wk, 0, l, a0, a1);
  { float2 bb=*(const float2*)(bk+2*l);
    #pragma unroll
    for(int e=0;e<RB;++e) ko[(size_t)(base+e)*64 + l] = packbf(a0[e]+bb.x, a1[e]+bb.y); }
  // V
  #pragma unroll
  for(int e=0;e<RB;++e){a0[e]=0.f;a1[e]=0.f;}
  gemm2<DH,DH>(at, Wv, 0, l, a0, a1);
  { float2 bb=*(const float2*)(bv+2*l);
    #pragma unroll
    for(int e=0;e<RB;++e) vo[(size_t)(base+e)*64 + l] = packbf(a0[e]+bb.x, a1[e]+bb.y); }
}

// ---------------- K2: fused edge pass ----------------
__global__ __launch_bounds__(64)
void k_edge(const float* __restrict__ ein,
            const float* __restrict__ We, const float* __restrict__ be,
            const float* __restrict__ Wg, const float* __restrict__ bgp,
            const float* __restrict__ Woe, const float* __restrict__ boe,
            const float* __restrict__ lg, const float* __restrict__ lb,
            const int* __restrict__ eidx,
            const u32* __restrict__ qv, const u32* __restrict__ kv, const u32* __restrict__ vv,
            float* __restrict__ accN, float* __restrict__ ssum,
            float* __restrict__ eout)
{
  __shared__ __align__(16) float at[DH][AP];
  __shared__ __align__(16) float st[DH][AP];
  const int l = threadIdx.x;
  const int base = blockIdx.x * RB;
  float ei0[RB], ei1[RB];
  { float2 g = *(const float2*)(lg+2*l);
    float2 b = *(const float2*)(lb+2*l);
    ln_rows<true>(ein, base, l, g.x, g.y, b.x, b.y, at, ei0, ei1); }
  __syncthreads();

  float a0[RB], a1[RB];
  // gate = sigmoid(LN(e)@Wg + bg)
  #pragma unroll
  for(int e=0;e<RB;++e){a0[e]=0.f;a1[e]=0.f;}
  gemm2<DH,DH>(at, Wg, 0, l, a0, a1);
  float gt0[RB], gt1[RB];
  { float2 bb=*(const float2*)(bgp+2*l);
    #pragma unroll
    for(int e=0;e<RB;++e){
      gt0[e] = 1.f/(1.f+__expf(-(a0[e]+bb.x)));
      gt1[e] = 1.f/(1.f+__expf(-(a1[e]+bb.y)));
    } }

  // ea = LN(e)@We + be ; s_elt = q[dst]*k[src] + ea ; scores -> esc ; ssum atomics
  #pragma unroll
  for(int e=0;e<RB;++e){a0[e]=0.f;a1[e]=0.f;}
  gemm2<DH,DH>(at, We, 0, l, a0, a1);
  float esc[RB];
  { float2 bb=*(const float2*)(be+2*l);
    #pragma unroll
    for(int e=0;e<RB;++e){
      int s_ = eidx[base+e], d_ = eidx[NE+base+e];
      u32 qw = qv[(size_t)d_*64+l], kw = kv[(size_t)s_*64+l];
      float s0 = a0[e]+bb.x + bflo(qw)*bflo(kw);
      float s1 = a1[e]+bb.y + bfhi(qw)*bfhi(kw);
      st[2*l][e]=s0; st[2*l+1][e]=s1;
      float ps = s0+s1;               // partial over this lane's 2 cols
      #pragma unroll
      for(int o=1;o<8;o<<=1) ps += __shfl_xor(ps,o);  // 8-lane group = one head (16 cols)
      float sc = fminf(fmaxf(ps*0.25f,-5.f),5.f);
      float ev = __expf(sc);          // clip to [-5,5] => no max-subtract needed
      esc[e]=ev;
      if ((l&7)==0) atomicAdd(&ssum[(size_t)d_*NHEAD + (l>>3)], ev);
    } }

  // numerator aggregation: acc[dst] += esc * v[src] * gate
  #pragma unroll
  for(int e=0;e<RB;++e){
    int s_ = eidx[base+e], d_ = eidx[NE+base+e];
    u32 vw = vv[(size_t)s_*64+l];
    float c0 = esc[e]*bflo(vw)*gt0[e];
    float c1 = esc[e]*bfhi(vw)*gt1[e];
    atomicAdd(&accN[(size_t)d_*DH + 2*l],   c0);
    atomicAdd(&accN[(size_t)d_*DH + 2*l+1], c1);
  }
  __syncthreads();

  // e_out = e_in + s_elt@Woe + boe
  #pragma unroll
  for(int e=0;e<RB;++e){a0[e]=0.f;a1[e]=0.f;}
  gemm2<DH,DH>(st, Woe, 0, l, a0, a1);
  { float2 bb=*(const float2*)(boe+2*l);
    #pragma unroll
    for(int e=0;e<RB;++e){
      float2 o; o.x = ei0[e]+a0[e]+bb.x; o.y = ei1[e]+a1[e]+bb.y;
      *(float2*)(eout + (size_t)(base+e)*DH + 2*l) = o;
    } }
}

// ---------------- K3: node epilogue: out/ssum, Wo, LN2, FFN ----------------
__global__ __launch_bounds__(64)
void k_out(const float* __restrict__ xin,
           const float* __restrict__ accN, const float* __restrict__ ssum,
           const float* __restrict__ Wo, const float* __restrict__ bo,
           const float* __restrict__ lg2, const float* __restrict__ lb2,
           const float* __restrict__ W1, const float* __restrict__ b1p,
           const float* __restrict__ W2, const float* __restrict__ b2p,
           float* __restrict__ xout)
{
  __shared__ __align__(16) float at[DH][AP];
  __shared__ __align__(16) float ht[2*DH][AP];
  const int l = threadIdx.x;
  const int base = blockIdx.x*RB;

  #pragma unroll
  for(int e=0;e<RB;++e){
    int n = base+e;
    float den = ssum[(size_t)n*NHEAD + (l>>3)];
    float inv = den>0.f ? 1.f/den : 0.f;   // zero in-degree -> out=0 (segment_sum semantics)
    at[2*l][e]   = accN[(size_t)n*DH+2*l]*inv;
    at[2*l+1][e] = accN[(size_t)n*DH+2*l+1]*inv;
  }
  __syncthreads();

  float a0[RB], a1[RB];
  #pragma unroll
  for(int e=0;e<RB;++e){a0[e]=0.f;a1[e]=0.f;}
  gemm2<DH,DH>(at, Wo, 0, l, a0, a1);
  float xm0[RB], xm1[RB];
  { float2 bb=*(const float2*)(bo+2*l);
    #pragma unroll
    for(int e=0;e<RB;++e){
      float2 xr = *(const float2*)(xin + (size_t)(base+e)*DH + 2*l);
      xm0[e] = xr.x+a0[e]+bb.x;
      xm1[e] = xr.y+a1[e]+bb.y;
    } }
  __syncthreads();

  // LN2 into at
  { float2 g=*(const float2*)(lg2+2*l); float2 b=*(const float2*)(lb2+2*l);
    for(int e=0;e<RB;++e){
      float s  = wred64(xm0[e]+xm1[e]);
      float s2 = wred64(xm0[e]*xm0[e]+xm1[e]*xm1[e]);
      float mu=s*(1.f/DH), var=fmaxf(s2*(1.f/DH)-mu*mu,0.f);
      float rs=rsqrtf(var+1e-5f);
      at[2*l][e]=(xm0[e]-mu)*rs*g.x+b.x;
      at[2*l+1][e]=(xm1[e]-mu)*rs*g.y+b.y;
    } }
  __syncthreads();

  // FFN layer 1 (two column halves of 256), relu, into ht
  float h0[RB], h1[RB];
  #pragma unroll
  for(int e=0;e<RB;++e){h0[e]=0.f;h1[e]=0.f;}
  gemm2<DH,2*DH>(at, W1, 0, l, h0, h1);
  { float2 bb=*(const float2*)(b1p+2*l);
    #pragma unroll
    for(int e=0;e<RB;++e){
      ht[2*l][e]   = fmaxf(h0[e]+bb.x, 0.f);
      ht[2*l+1][e] = fmaxf(h1[e]+bb.y, 0.f);
    } }
  #pragma unroll
  for(int e=0;e<RB;++e){h0[e]=0.f;h1[e]=0.f;}
  gemm2<DH,2*DH>(at, W1, DH, l, h0, h1);
  { float2 bb=*(const float2*)(b1p+DH+2*l);
    #pragma unroll
    for(int e=0;e<RB;++e){
      ht[DH+2*l][e]   = fmaxf(h0[e]+bb.x, 0.f);
      ht[DH+2*l+1][e] = fmaxf(h1[e]+bb.y, 0.f);
    } }
  __syncthreads();

  // FFN layer 2 (K=256) + residual
  #pragma unroll
  for(int e=0;e<RB;++e){a0[e]=0.f;a1[e]=0.f;}
  gemm2<2*DH,DH>(ht, W2, 0, l, a0, a1);
  { float2 bb=*(const float2*)(b2p+2*l);
    #pragma unroll
    for(int e=0;e<RB;++e){
      float2 o; o.x = xm0[e]+a0[e]+bb.x; o.y = xm1[e]+a1[e]+bb.y;
      *(float2*)(xout + (size_t)(base+e)*DH + 2*l) = o;
    } }
}

extern "C" void kernel_launch(void* const* d_in, const int* in_sizes, int n_in,
                              void* d_out, int out_size, void* d_ws, size_t ws_size,
                              hipStream_t stream) {
  (void)in_sizes; (void)n_in; (void)out_size; (void)ws_size;
  const float* xin = (const float*)d_in[0];
  const float* ein = (const float*)d_in[1];
  const float* Wq = (const float*)d_in[2];  const float* bq = (const float*)d_in[3];
  const float* Wk = (const float*)d_in[4];  const float* bk = (const float*)d_in[5];
  const float* Wv = (const float*)d_in[6];  const float* bv = (const float*)d_in[7];
  const float* We = (const float*)d_in[8];  const float* be = (const float*)d_in[9];
  const float* Wg = (const float*)d_in[10]; const float* bg = (const float*)d_in[11];
  const float* Wo = (const float*)d_in[12]; const float* bo = (const float*)d_in[13];
  const float* Woe= (const float*)d_in[14]; const float* boe= (const float*)d_in[15];
  const float* l1g= (const float*)d_in[16]; const float* l1b= (const float*)d_in[17];
  const float* l1eg=(const float*)d_in[18]; const float* l1eb=(const float*)d_in[19];
  const float* l2g= (const float*)d_in[20]; const float* l2b= (const float*)d_in[21];
  const float* W1 = (const float*)d_in[22]; const float* b1 = (const float*)d_in[23];
  const float* W2 = (const float*)d_in[24]; const float* b2 = (const float*)d_in[25];
  const int* eidx = (const int*)d_in[26];

  float* xout = (float*)d_out;
  float* eout = xout + (size_t)NN*DH;
  float* accN = xout;                      // x_out region doubles as accN scratch

  // ws layout: ssum [NN*8 f32] | q,k,v bf16-packed [NN*64 u32 each]  (~40 MB)
  float* ssum = (float*)d_ws;
  u32* qv = (u32*)(ssum + (size_t)NN*NHEAD);
  u32* kv = qv + (size_t)NN*64;
  u32* vv = kv + (size_t)NN*64;

  hipMemsetAsync(accN, 0, (size_t)NN*DH*sizeof(float), stream);
  hipMemsetAsync(ssum, 0, (size_t)NN*NHEAD*sizeof(float), stream);

  k_qkv<<<NN/RB, 64, 0, stream>>>(xin, Wq,bq, Wk,bk, Wv,bv, l1g,l1b, qv,kv,vv);
  k_edge<<<NE/RB, 64, 0, stream>>>(ein, We,be, Wg,bg, Woe,boe, l1eg,l1eb,
                                   eidx, qv,kv,vv, accN, ssum, eout);
  k_out<<<NN/RB, 64, 0, stream>>>(xin, accN, ssum, Wo,bo, l2g,l2b, W1,b1, W2,b2, xout);
}

// Round 3
// 1089.509 us; speedup vs baseline: 1.1600x; 1.1600x over previous
//
#include <hip/hip_runtime.h>

#define NN 50000
#define NE 400000

typedef unsigned int u32;
typedef unsigned short u16;
typedef __attribute__((ext_vector_type(8))) short short8; // 8 bf16 = 4 VGPR
typedef __attribute__((ext_vector_type(4))) float f32x4;

union FragU { uint4 u; short8 s; };

__device__ __forceinline__ float bflo(u32 w){ union{u32 i; float f;} v; v.i = w<<16; return v.f; }
__device__ __forceinline__ float bfhi(u32 w){ union{u32 i; float f;} v; v.i = w & 0xffff0000u; return v.f; }
__device__ __forceinline__ u32 packbf(float a, float b){
  union{float f;u32 i;} x, y; x.f=a; y.f=b;
  u32 xi = x.i + (((x.i>>16)&1u) + 0x7fffu);
  u32 yi = y.i + (((y.i>>16)&1u) + 0x7fffu);
  return (xi>>16) | (yi & 0xffff0000u);
}

// swizzled dword index in a [rows][128]-bf16 tile (64 u32/row); XOR spreads rows over banks
__device__ __forceinline__ int swz64(int row, int cp){ return row*64 + (cp ^ ((row&7)<<2)); }
// same for [rows][256]-bf16 tile (128 u32/row)
__device__ __forceinline__ int swz128(int row, int cp){ return row*128 + (cp ^ ((row&7)<<2)); }

// Stage 64 rows (f32, stride 128) with LayerNorm -> bf16 swizzled tile. 4 threads/row.
__device__ __forceinline__ void stage_ln(const float* __restrict__ src, long base, long nrows,
                                         const float* __restrict__ gam, const float* __restrict__ bet,
                                         u32* __restrict__ tile, int t)
{
  int row = t>>2, sub = t&3;
  bool valid = (base + row) < nrows;
  const float* p = src + (base+row)*128 + sub*32;
  float4 x[8];
  float s=0.f, s2=0.f;
  #pragma unroll
  for(int q=0;q<8;++q){
    x[q] = valid ? *(const float4*)(p + 4*q) : make_float4(0.f,0.f,0.f,0.f);
    s  += x[q].x + x[q].y + x[q].z + x[q].w;
    s2 += x[q].x*x[q].x + x[q].y*x[q].y + x[q].z*x[q].z + x[q].w*x[q].w;
  }
  s  += __shfl_xor(s,1);  s  += __shfl_xor(s,2);
  s2 += __shfl_xor(s2,1); s2 += __shfl_xor(s2,2);
  float mu  = s*(1.f/128.f);
  float var = fmaxf(s2*(1.f/128.f) - mu*mu, 0.f);
  float rs  = rsqrtf(var + 1e-5f);
  const float* gp = gam + sub*32; const float* bp = bet + sub*32;
  #pragma unroll
  for(int m4=0;m4<4;++m4){
    float4 g0 = *(const float4*)(gp + 8*m4);
    float4 g1 = *(const float4*)(gp + 8*m4 + 4);
    float4 b0 = *(const float4*)(bp + 8*m4);
    float4 b1 = *(const float4*)(bp + 8*m4 + 4);
    float4 xa = x[2*m4], xb = x[2*m4+1];
    uint4 wv;
    wv.x = packbf((xa.x-mu)*rs*g0.x+b0.x, (xa.y-mu)*rs*g0.y+b0.y);
    wv.y = packbf((xa.z-mu)*rs*g0.z+b0.z, (xa.w-mu)*rs*g0.w+b0.w);
    wv.z = packbf((xb.x-mu)*rs*g1.x+b1.x, (xb.y-mu)*rs*g1.y+b1.y);
    wv.w = packbf((xb.z-mu)*rs*g1.z+b1.z, (xb.w-mu)*rs*g1.w+b1.w);
    *(uint4*)&tile[swz64(row, sub*16 + m4*4)] = wv;
  }
}

// D^T = W^T (A-op, packed PW) x data (B-op from swizzled tile). 8 mt tiles, K=128.
__device__ __forceinline__ void gemmT8(const u16* __restrict__ PW, int NT, int mtoff,
                                       const u32* __restrict__ tile, int row, int l,
                                       f32x4 acc[8])
{
  int g = l>>4;
  #pragma unroll
  for(int kc=0;kc<4;++kc){
    FragU bf; bf.u = *(const uint4*)&tile[swz64(row, kc*16 + g*4)];
    #pragma unroll
    for(int mt=0;mt<8;++mt){
      FragU af; af.u = ((const uint4*)PW)[(size_t)(kc*NT + mtoff + mt)*64 + l];
      acc[mt] = __builtin_amdgcn_mfma_f32_16x16x32_bf16(af.s, bf.s, acc[mt], 0,0,0);
    }
  }
}

// K=256 variant (8 kc) reading from [64][256] tile
__device__ __forceinline__ void gemmT8_k256(const u16* __restrict__ PW,
                                            const u32* __restrict__ tile, int row, int l,
                                            f32x4 acc[8])
{
  int g = l>>4;
  #pragma unroll
  for(int kc=0;kc<8;++kc){
    FragU bf; bf.u = *(const uint4*)&tile[swz128(row, kc*16 + g*4)];
    #pragma unroll
    for(int mt=0;mt<8;++mt){
      FragU af; af.u = ((const uint4*)PW)[(size_t)(kc*8 + mt)*64 + l];
      acc[mt] = __builtin_amdgcn_mfma_f32_16x16x32_bf16(af.s, bf.s, acc[mt], 0,0,0);
    }
  }
}

// Pack f32 weight [K][N] into MFMA A-fragment order (bf16):
// PW[((kc*(N/16)+nt)*64+l)*8+j] = bf16(W[kc*32+(l>>4)*8+j][nt*16+(l&15)])
__global__ __launch_bounds__(256)
void k_pack(const float* __restrict__ src, u16* __restrict__ dst, int K, int N){
  int i = blockIdx.x*256 + threadIdx.x;
  if (i >= K*N) return;
  int j = i & 7, l = (i>>3) & 63;
  int rest = i >> 9;
  int NT = N >> 4;
  int nt = rest % NT, kc = rest / NT;
  int k = kc*32 + (l>>4)*8 + j;
  int n = nt*16 + (l&15);
  union{float f;u32 u;} x; x.f = src[(size_t)k*N + n];
  u32 r = (x.u + (((x.u>>16)&1u) + 0x7fffu)) >> 16;
  dst[i] = (u16)r;
}

// ---------------- K1: node LN + q,k,v projections (bf16-packed) ----------------
__global__ __launch_bounds__(256)
void k_qkv(const float* __restrict__ xin,
           const float* __restrict__ l1g, const float* __restrict__ l1b,
           const u16* __restrict__ pWq, const float* __restrict__ bq,
           const u16* __restrict__ pWk, const float* __restrict__ bk,
           const u16* __restrict__ pWv, const float* __restrict__ bv,
           u32* __restrict__ qv, u32* __restrict__ kv, u32* __restrict__ vv)
{
  __shared__ u32 tile[64*64];
  int t = threadIdx.x;
  long base = (long)blockIdx.x * 64;
  stage_ln(xin, base, NN, l1g, l1b, tile, t);
  __syncthreads();
  int w = t>>6, l = t&63, g = l>>4;
  int row = w*16 + (l&15);
  long node = base + row;
  bool valid = node < NN;

  f32x4 acc[8];
  const u16* pws[3] = {pWq, pWk, pWv};
  const float* bbs[3] = {bq, bk, bv};
  u32* outs[3] = {qv, kv, vv};
  #pragma unroll
  for(int s3=0;s3<3;++s3){
    #pragma unroll
    for(int mt=0;mt<8;++mt) acc[mt] = (f32x4){0.f,0.f,0.f,0.f};
    gemmT8(pws[s3], 8, 0, tile, row, l, acc);
    if (valid){
      u32* op = outs[s3] + node*64;
      #pragma unroll
      for(int mt=0;mt<8;++mt){
        float4 bb = *(const float4*)(bbs[s3] + mt*16 + g*4);
        uint2 o;
        o.x = packbf(acc[mt][0]+bb.x, acc[mt][1]+bb.y);
        o.y = packbf(acc[mt][2]+bb.z, acc[mt][3]+bb.w);
        *(uint2*)(op + mt*8 + g*2) = o;
      }
    }
  }
}

// ---------------- K2: fused edge pass ----------------
__global__ __launch_bounds__(256)
void k_edge(const float* __restrict__ ein,
            const float* __restrict__ l1eg, const float* __restrict__ l1eb,
            const u16* __restrict__ pWg, const float* __restrict__ bg,
            const u16* __restrict__ pWe, const float* __restrict__ be,
            const u16* __restrict__ pWoe, const float* __restrict__ boe,
            const int* __restrict__ eidx,
            const u32* __restrict__ qv, const u32* __restrict__ kv, const u32* __restrict__ vv,
            float* __restrict__ accN, float* __restrict__ ssum,
            float* __restrict__ eout)
{
  __shared__ u32 tile[64*64];
  int t = threadIdx.x;
  long base = (long)blockIdx.x * 64;
  stage_ln(ein, base, NE, l1eg, l1eb, tile, t);
  __syncthreads();
  int w = t>>6, l = t&63, g = l>>4;
  int row = w*16 + (l&15);
  long edge = base + row;
  int s_ = eidx[edge], d_ = eidx[NE + edge];
  const u32* qrow = qv + (size_t)d_*64;
  const u32* krow = kv + (size_t)s_*64;
  const u32* vrow = vv + (size_t)s_*64;

  f32x4 acc[8], gate[8];
  // gate = sigmoid(LN(e)@Wg + bg)   (transposed: per-lane feats mt*16+g*4+r of edge l&15)
  #pragma unroll
  for(int mt=0;mt<8;++mt) acc[mt] = (f32x4){0.f,0.f,0.f,0.f};
  gemmT8(pWg, 8, 0, tile, row, l, acc);
  #pragma unroll
  for(int mt=0;mt<8;++mt){
    float4 bb = *(const float4*)(bg + mt*16 + g*4);
    gate[mt][0] = 1.f/(1.f+__expf(-(acc[mt][0]+bb.x)));
    gate[mt][1] = 1.f/(1.f+__expf(-(acc[mt][1]+bb.y)));
    gate[mt][2] = 1.f/(1.f+__expf(-(acc[mt][2]+bb.z)));
    gate[mt][3] = 1.f/(1.f+__expf(-(acc[mt][3]+bb.w)));
  }
  // s_elt = LN(e)@We + be + q[dst]*k[src]; scores -> esc; ssum atomics
  #pragma unroll
  for(int mt=0;mt<8;++mt) acc[mt] = (f32x4){0.f,0.f,0.f,0.f};
  gemmT8(pWe, 8, 0, tile, row, l, acc);
  float esc[8];
  #pragma unroll
  for(int mt=0;mt<8;++mt){
    float4 bb = *(const float4*)(be + mt*16 + g*4);
    uint2 qw = *(const uint2*)(qrow + mt*8 + g*2);
    uint2 kw = *(const uint2*)(krow + mt*8 + g*2);
    acc[mt][0] += bb.x + bflo(qw.x)*bflo(kw.x);
    acc[mt][1] += bb.y + bfhi(qw.x)*bfhi(kw.x);
    acc[mt][2] += bb.z + bflo(qw.y)*bflo(kw.y);
    acc[mt][3] += bb.w + bfhi(qw.y)*bfhi(kw.y);
    float ps = acc[mt][0]+acc[mt][1]+acc[mt][2]+acc[mt][3];
    ps += __shfl_xor(ps, 16);
    ps += __shfl_xor(ps, 32);                  // sum over all 16 feats of head mt
    float sc = fminf(fmaxf(ps*0.25f, -5.f), 5.f);
    float ev = __expf(sc);                     // clipped => no max-subtract needed
    esc[mt] = ev;
    if (g==0) atomicAdd(&ssum[(size_t)d_*8 + mt], ev);
  }
  // numerator: acc[dst] += esc * gate * v[src]
  #pragma unroll
  for(int mt=0;mt<8;++mt){
    uint2 vw = *(const uint2*)(vrow + mt*8 + g*2);
    float e0 = esc[mt];
    float c0 = e0*gate[mt][0]*bflo(vw.x);
    float c1 = e0*gate[mt][1]*bfhi(vw.x);
    float c2 = e0*gate[mt][2]*bflo(vw.y);
    float c3 = e0*gate[mt][3]*bfhi(vw.y);
    float* ap = accN + (size_t)d_*128 + mt*16 + g*4;
    atomicAdd(ap+0,c0); atomicAdd(ap+1,c1); atomicAdd(ap+2,c2); atomicAdd(ap+3,c3);
  }
  __syncthreads();                 // all waves done reading LN tile
  // write s_elt (bf16) into tile (A-layout for Woe GEMM)
  #pragma unroll
  for(int mt=0;mt<8;++mt){
    uint2 o;
    o.x = packbf(acc[mt][0], acc[mt][1]);
    o.y = packbf(acc[mt][2], acc[mt][3]);
    *(uint2*)&tile[swz64(row, mt*8 + g*2)] = o;
  }
  __syncthreads();
  // e_out = e_in + s_elt@Woe + boe
  f32x4 oacc[8];
  #pragma unroll
  for(int mt=0;mt<8;++mt) oacc[mt] = (f32x4){0.f,0.f,0.f,0.f};
  gemmT8(pWoe, 8, 0, tile, row, l, oacc);
  #pragma unroll
  for(int mt=0;mt<8;++mt){
    float4 bb = *(const float4*)(boe + mt*16 + g*4);
    float4 er = *(const float4*)(ein + edge*128 + mt*16 + g*4);
    float4 o;
    o.x = er.x + oacc[mt][0] + bb.x;
    o.y = er.y + oacc[mt][1] + bb.y;
    o.z = er.z + oacc[mt][2] + bb.z;
    o.w = er.w + oacc[mt][3] + bb.w;
    *(float4*)(eout + edge*128 + mt*16 + g*4) = o;
  }
}

// ---------------- K3: node epilogue: normalize, Wo, LN2, FFN ----------------
__global__ __launch_bounds__(256)
void k_out(const float* __restrict__ xin,
           const float* __restrict__ accN, const float* __restrict__ ssum,
           const u16* __restrict__ pWo, const float* __restrict__ bo,
           const float* __restrict__ l2g, const float* __restrict__ l2b,
           const u16* __restrict__ pW1, const float* __restrict__ b1p,
           const u16* __restrict__ pW2, const float* __restrict__ b2p,
           float* __restrict__ xout)
{
  __shared__ u32 tile[64*64];
  __shared__ u32 htile[64*128];
  int t = threadIdx.x;
  long base = (long)blockIdx.x * 64;
  // stage normalized attention output (accN/ssum) -> bf16 tile
  {
    int row = t>>2, sub = t&3;
    long node = base + row;
    bool valid = node < NN;
    float inv0 = 0.f, inv1 = 0.f;
    if (valid){
      float d0 = ssum[node*8 + sub*2], d1 = ssum[node*8 + sub*2 + 1];
      inv0 = d0 > 0.f ? 1.f/d0 : 0.f;
      inv1 = d1 > 0.f ? 1.f/d1 : 0.f;
    }
    const float* p = accN + node*128 + sub*32;
    #pragma unroll
    for(int m4=0;m4<4;++m4){
      float inv = (m4 < 2) ? inv0 : inv1;
      float4 xa = valid ? *(const float4*)(p + 8*m4)     : make_float4(0.f,0.f,0.f,0.f);
      float4 xb = valid ? *(const float4*)(p + 8*m4 + 4) : make_float4(0.f,0.f,0.f,0.f);
      uint4 wv;
      wv.x = packbf(xa.x*inv, xa.y*inv);
      wv.y = packbf(xa.z*inv, xa.w*inv);
      wv.z = packbf(xb.x*inv, xb.y*inv);
      wv.w = packbf(xb.z*inv, xb.w*inv);
      *(uint4*)&tile[swz64(row, sub*16 + m4*4)] = wv;
    }
  }
  __syncthreads();
  int w = t>>6, l = t&63, g = l>>4;
  int row = w*16 + (l&15);
  long node = base + row;
  bool valid = node < NN;

  // Wo GEMM; xmid = x_in + out@Wo + bo
  f32x4 acc[8], xm[8];
  #pragma unroll
  for(int mt=0;mt<8;++mt) acc[mt] = (f32x4){0.f,0.f,0.f,0.f};
  gemmT8(pWo, 8, 0, tile, row, l, acc);
  #pragma unroll
  for(int mt=0;mt<8;++mt){
    float4 bb = *(const float4*)(bo + mt*16 + g*4);
    float4 xr = valid ? *(const float4*)(xin + node*128 + mt*16 + g*4) : make_float4(0.f,0.f,0.f,0.f);
    xm[mt][0] = xr.x + acc[mt][0] + bb.x;
    xm[mt][1] = xr.y + acc[mt][1] + bb.y;
    xm[mt][2] = xr.z + acc[mt][2] + bb.z;
    xm[mt][3] = xr.w + acc[mt][3] + bb.w;
  }
  // LN2 in-register (stats per node over 128 feats: local 32 + cross-group shfl)
  float s=0.f, s2=0.f;
  #pragma unroll
  for(int mt=0;mt<8;++mt){
    s  += xm[mt][0]+xm[mt][1]+xm[mt][2]+xm[mt][3];
    s2 += xm[mt][0]*xm[mt][0]+xm[mt][1]*xm[mt][1]+xm[mt][2]*xm[mt][2]+xm[mt][3]*xm[mt][3];
  }
  s  += __shfl_xor(s,16);  s  += __shfl_xor(s,32);
  s2 += __shfl_xor(s2,16); s2 += __shfl_xor(s2,32);
  float mu  = s*(1.f/128.f);
  float var = fmaxf(s2*(1.f/128.f) - mu*mu, 0.f);
  float rs  = rsqrtf(var + 1e-5f);
  __syncthreads();              // done reading tile (Wo B-frags)
  #pragma unroll
  for(int mt=0;mt<8;++mt){
    float4 gg = *(const float4*)(l2g + mt*16 + g*4);
    float4 bb = *(const float4*)(l2b + mt*16 + g*4);
    float h0 = (xm[mt][0]-mu)*rs*gg.x + bb.x;
    float h1 = (xm[mt][1]-mu)*rs*gg.y + bb.y;
    float h2 = (xm[mt][2]-mu)*rs*gg.z + bb.z;
    float h3 = (xm[mt][3]-mu)*rs*gg.w + bb.w;
    uint2 o; o.x = packbf(h0,h1); o.y = packbf(h2,h3);
    *(uint2*)&tile[swz64(row, mt*8 + g*2)] = o;
  }
  __syncthreads();
  // FFN layer 1 (256 outs in two halves), relu -> htile
  #pragma unroll
  for(int half=0; half<2; ++half){
    f32x4 dh[8];
    #pragma unroll
    for(int mt=0;mt<8;++mt) dh[mt] = (f32x4){0.f,0.f,0.f,0.f};
    gemmT8(pW1, 16, half*8, tile, row, l, dh);
    #pragma unroll
    for(int mt=0;mt<8;++mt){
      int feat = half*128 + mt*16 + g*4;
      float4 bb = *(const float4*)(b1p + feat);
      float h0 = fmaxf(dh[mt][0]+bb.x, 0.f);
      float h1 = fmaxf(dh[mt][1]+bb.y, 0.f);
      float h2 = fmaxf(dh[mt][2]+bb.z, 0.f);
      float h3 = fmaxf(dh[mt][3]+bb.w, 0.f);
      uint2 o; o.x = packbf(h0,h1); o.y = packbf(h2,h3);
      *(uint2*)&htile[swz128(row, feat>>1)] = o;
    }
  }
  __syncthreads();
  // FFN layer 2 (K=256) + residual
  f32x4 oacc[8];
  #pragma unroll
  for(int mt=0;mt<8;++mt) oacc[mt] = (f32x4){0.f,0.f,0.f,0.f};
  gemmT8_k256(pW2, htile, row, l, oacc);
  if (valid){
    #pragma unroll
    for(int mt=0;mt<8;++mt){
      float4 bb = *(const float4*)(b2p + mt*16 + g*4);
      float4 o;
      o.x = xm[mt][0] + oacc[mt][0] + bb.x;
      o.y = xm[mt][1] + oacc[mt][1] + bb.y;
      o.z = xm[mt][2] + oacc[mt][2] + bb.z;
      o.w = xm[mt][3] + oacc[mt][3] + bb.w;
      *(float4*)(xout + node*128 + mt*16 + g*4) = o;
    }
  }
}

extern "C" void kernel_launch(void* const* d_in, const int* in_sizes, int n_in,
                              void* d_out, int out_size, void* d_ws, size_t ws_size,
                              hipStream_t stream) {
  (void)in_sizes; (void)n_in; (void)out_size; (void)ws_size;
  const float* xin = (const float*)d_in[0];
  const float* ein = (const float*)d_in[1];
  const float* Wq = (const float*)d_in[2];  const float* bq = (const float*)d_in[3];
  const float* Wk = (const float*)d_in[4];  const float* bk = (const float*)d_in[5];
  const float* Wv = (const float*)d_in[6];  const float* bv = (const float*)d_in[7];
  const float* We = (const float*)d_in[8];  const float* be = (const float*)d_in[9];
  const float* Wg = (const float*)d_in[10]; const float* bg = (const float*)d_in[11];
  const float* Wo = (const float*)d_in[12]; const float* bo = (const float*)d_in[13];
  const float* Woe= (const float*)d_in[14]; const float* boe= (const float*)d_in[15];
  const float* l1g= (const float*)d_in[16]; const float* l1b= (const float*)d_in[17];
  const float* l1eg=(const float*)d_in[18]; const float* l1eb=(const float*)d_in[19];
  const float* l2g= (const float*)d_in[20]; const float* l2b= (const float*)d_in[21];
  const float* W1 = (const float*)d_in[22]; const float* b1 = (const float*)d_in[23];
  const float* W2 = (const float*)d_in[24]; const float* b2 = (const float*)d_in[25];
  const int* eidx = (const int*)d_in[26];

  float* xout = (float*)d_out;
  float* eout = xout + (size_t)NN*128;
  float* accN = xout;                        // x_out region doubles as f32 accN scratch

  // ws: ssum [NN*8 f32] | qv,kv,vv [NN*64 u32 each] | packed weights (bf16)
  float* ssum = (float*)d_ws;
  u32* qv = (u32*)(ssum + (size_t)NN*8);
  u32* kv = qv + (size_t)NN*64;
  u32* vv = kv + (size_t)NN*64;
  u16* pw  = (u16*)(vv + (size_t)NN*64);
  u16* pWq = pw;            u16* pWk = pWq + 16384;  u16* pWv = pWk + 16384;
  u16* pWe = pWv + 16384;   u16* pWg = pWe + 16384;  u16* pWoe= pWg + 16384;
  u16* pWo = pWoe + 16384;  u16* pW1 = pWo + 16384;  u16* pW2 = pW1 + 32768;

  k_pack<<<64, 256, 0, stream>>>(Wq,  pWq, 128, 128);
  k_pack<<<64, 256, 0, stream>>>(Wk,  pWk, 128, 128);
  k_pack<<<64, 256, 0, stream>>>(Wv,  pWv, 128, 128);
  k_pack<<<64, 256, 0, stream>>>(We,  pWe, 128, 128);
  k_pack<<<64, 256, 0, stream>>>(Wg,  pWg, 128, 128);
  k_pack<<<64, 256, 0, stream>>>(Woe, pWoe,128, 128);
  k_pack<<<64, 256, 0, stream>>>(Wo,  pWo, 128, 128);
  k_pack<<<128,256, 0, stream>>>(W1,  pW1, 128, 256);
  k_pack<<<128,256, 0, stream>>>(W2,  pW2, 256, 128);

  hipMemsetAsync(accN, 0, (size_t)NN*128*sizeof(float), stream);
  hipMemsetAsync(ssum, 0, (size_t)NN*8*sizeof(float), stream);

  k_qkv<<<(NN+63)/64, 256, 0, stream>>>(xin, l1g, l1b, pWq, bq, pWk, bk, pWv, bv, qv, kv, vv);
  k_edge<<<NE/64, 256, 0, stream>>>(ein, l1eg, l1eb, pWg, bg, pWe, be, pWoe, boe,
                                    eidx, qv, kv, vv, accN, ssum, eout);
  k_out<<<(NN+63)/64, 256, 0, stream>>>(xin, accN, ssum, pWo, bo, l2g, l2b,
                                        pW1, b1, pW2, b2, xout);
}

// Round 4
// 745.455 us; speedup vs baseline: 1.6955x; 1.4615x over previous
//
#include <hip/hip_runtime.h>

#define NN 50000
#define NE 400000

typedef unsigned int u32;
typedef unsigned short u16;
typedef __attribute__((ext_vector_type(8))) short short8; // 8 bf16 = 4 VGPR
typedef __attribute__((ext_vector_type(4))) float f32x4;

union FragU { uint4 u; short8 s; };

__device__ __forceinline__ float bflo(u32 w){ union{u32 i; float f;} v; v.i = w<<16; return v.f; }
__device__ __forceinline__ float bfhi(u32 w){ union{u32 i; float f;} v; v.i = w & 0xffff0000u; return v.f; }
__device__ __forceinline__ u32 packbf(float a, float b){
  union{float f;u32 i;} x, y; x.f=a; y.f=b;
  u32 xi = x.i + (((x.i>>16)&1u) + 0x7fffu);
  u32 yi = y.i + (((y.i>>16)&1u) + 0x7fffu);
  return (xi>>16) | (yi & 0xffff0000u);
}

// swizzled dword index in a [rows][128]-bf16 tile (64 u32/row)
__device__ __forceinline__ int swz64(int row, int cp){ return row*64 + (cp ^ ((row&7)<<2)); }
// same for [rows][256]-bf16 tile (128 u32/row)
__device__ __forceinline__ int swz128(int row, int cp){ return row*128 + (cp ^ ((row&7)<<2)); }

// Stage 64 rows (f32, stride 128) with LayerNorm -> bf16 swizzled tile. 4 threads/row.
__device__ __forceinline__ void stage_ln(const float* __restrict__ src, long base, long nrows,
                                         const float* __restrict__ gam, const float* __restrict__ bet,
                                         u32* __restrict__ tile, int t)
{
  int row = t>>2, sub = t&3;
  bool valid = (base + row) < nrows;
  const float* p = src + (base+row)*128 + sub*32;
  float4 x[8];
  float s=0.f, s2=0.f;
  #pragma unroll
  for(int q=0;q<8;++q){
    x[q] = valid ? *(const float4*)(p + 4*q) : make_float4(0.f,0.f,0.f,0.f);
    s  += x[q].x + x[q].y + x[q].z + x[q].w;
    s2 += x[q].x*x[q].x + x[q].y*x[q].y + x[q].z*x[q].z + x[q].w*x[q].w;
  }
  s  += __shfl_xor(s,1);  s  += __shfl_xor(s,2);
  s2 += __shfl_xor(s2,1); s2 += __shfl_xor(s2,2);
  float mu  = s*(1.f/128.f);
  float var = fmaxf(s2*(1.f/128.f) - mu*mu, 0.f);
  float rs  = rsqrtf(var + 1e-5f);
  const float* gp = gam + sub*32; const float* bp = bet + sub*32;
  #pragma unroll
  for(int m4=0;m4<4;++m4){
    float4 g0 = *(const float4*)(gp + 8*m4);
    float4 g1 = *(const float4*)(gp + 8*m4 + 4);
    float4 b0 = *(const float4*)(bp + 8*m4);
    float4 b1 = *(const float4*)(bp + 8*m4 + 4);
    float4 xa = x[2*m4], xb = x[2*m4+1];
    uint4 wv;
    wv.x = packbf((xa.x-mu)*rs*g0.x+b0.x, (xa.y-mu)*rs*g0.y+b0.y);
    wv.y = packbf((xa.z-mu)*rs*g0.z+b0.z, (xa.w-mu)*rs*g0.w+b0.w);
    wv.z = packbf((xb.x-mu)*rs*g1.x+b1.x, (xb.y-mu)*rs*g1.y+b1.y);
    wv.w = packbf((xb.z-mu)*rs*g1.z+b1.z, (xb.w-mu)*rs*g1.w+b1.w);
    *(uint4*)&tile[swz64(row, sub*16 + m4*4)] = wv;
  }
}

// D^T = W^T (A-op, packed PW) x data (B-op from swizzled tile). 8 mt tiles, K=128.
__device__ __forceinline__ void gemmT8(const u16* __restrict__ PW, int NT, int mtoff,
                                       const u32* __restrict__ tile, int row, int l,
                                       f32x4 acc[8])
{
  int g = l>>4;
  #pragma unroll
  for(int kc=0;kc<4;++kc){
    FragU bf; bf.u = *(const uint4*)&tile[swz64(row, kc*16 + g*4)];
    #pragma unroll
    for(int mt=0;mt<8;++mt){
      FragU af; af.u = ((const uint4*)PW)[(size_t)(kc*NT + mtoff + mt)*64 + l];
      acc[mt] = __builtin_amdgcn_mfma_f32_16x16x32_bf16(af.s, bf.s, acc[mt], 0,0,0);
    }
  }
}

// K=256 variant (8 kc) reading from [64][256] tile
__device__ __forceinline__ void gemmT8_k256(const u16* __restrict__ PW,
                                            const u32* __restrict__ tile, int row, int l,
                                            f32x4 acc[8])
{
  int g = l>>4;
  #pragma unroll
  for(int kc=0;kc<8;++kc){
    FragU bf; bf.u = *(const uint4*)&tile[swz128(row, kc*16 + g*4)];
    #pragma unroll
    for(int mt=0;mt<8;++mt){
      FragU af; af.u = ((const uint4*)PW)[(size_t)(kc*8 + mt)*64 + l];
      acc[mt] = __builtin_amdgcn_mfma_f32_16x16x32_bf16(af.s, bf.s, acc[mt], 0,0,0);
    }
  }
}

// Pack f32 weight [K][N] into MFMA A-fragment order (bf16)
__global__ __launch_bounds__(256)
void k_pack(const float* __restrict__ src, u16* __restrict__ dst, int K, int N){
  int i = blockIdx.x*256 + threadIdx.x;
  if (i >= K*N) return;
  int j = i & 7, l = (i>>3) & 63;
  int rest = i >> 9;
  int NT = N >> 4;
  int nt = rest % NT, kc = rest / NT;
  int k = kc*32 + (l>>4)*8 + j;
  int n = nt*16 + (l&15);
  union{float f;u32 u;} x; x.f = src[(size_t)k*N + n];
  u32 r = (x.u + (((x.u>>16)&1u) + 0x7fffu)) >> 16;
  dst[i] = (u16)r;
}

// ---------------- CSR build ----------------
__global__ __launch_bounds__(256)
void k_deg(const int* __restrict__ eidx, int* __restrict__ deg){
  int e = blockIdx.x*256 + threadIdx.x;
  if (e < NE) atomicAdd(&deg[eidx[NE+e]], 1);
}

__global__ __launch_bounds__(1024)
void k_scan(const int* __restrict__ deg, int* __restrict__ starts, int* __restrict__ cursor){
  __shared__ int part[1024];
  int t = threadIdx.x;
  const int CH = (NN + 1023)/1024;
  int base = t*CH;
  int s = 0;
  for (int i=0;i<CH;++i){ int idx = base+i; if (idx < NN) s += deg[idx]; }
  part[t] = s; __syncthreads();
  for (int off=1; off<1024; off<<=1){
    int v = (t>=off) ? part[t-off] : 0;
    __syncthreads();
    part[t] += v;
    __syncthreads();
  }
  int pre = (t==0) ? 0 : part[t-1];
  for (int i=0;i<CH;++i){
    int idx = base+i;
    if (idx < NN){ starts[idx]=pre; cursor[idx]=pre; pre += deg[idx]; }
  }
}

__global__ __launch_bounds__(256)
void k_scatter(const int* __restrict__ eidx, int* __restrict__ cursor, int* __restrict__ elist){
  int e = blockIdx.x*256 + threadIdx.x;
  if (e < NE){
    int d = eidx[NE+e];
    int pos = atomicAdd(&cursor[d], 1);
    elist[pos] = e;
  }
}

// ---------------- K1: node LN + q,k,v projections (bf16-packed) ----------------
__global__ __launch_bounds__(256)
void k_qkv(const float* __restrict__ xin,
           const float* __restrict__ l1g, const float* __restrict__ l1b,
           const u16* __restrict__ pWq, const float* __restrict__ bq,
           const u16* __restrict__ pWk, const float* __restrict__ bk,
           const u16* __restrict__ pWv, const float* __restrict__ bv,
           u32* __restrict__ qv, u32* __restrict__ kv, u32* __restrict__ vv)
{
  __shared__ u32 tile[64*64];
  int t = threadIdx.x;
  long base = (long)blockIdx.x * 64;
  stage_ln(xin, base, NN, l1g, l1b, tile, t);
  __syncthreads();
  int w = t>>6, l = t&63, g = l>>4;
  int row = w*16 + (l&15);
  long node = base + row;
  bool valid = node < NN;

  f32x4 acc[8];
  const u16* pws[3] = {pWq, pWk, pWv};
  const float* bbs[3] = {bq, bk, bv};
  u32* outs[3] = {qv, kv, vv};
  #pragma unroll
  for(int s3=0;s3<3;++s3){
    #pragma unroll
    for(int mt=0;mt<8;++mt) acc[mt] = (f32x4){0.f,0.f,0.f,0.f};
    gemmT8(pws[s3], 8, 0, tile, row, l, acc);
    if (valid){
      u32* op = outs[s3] + node*64;
      #pragma unroll
      for(int mt=0;mt<8;++mt){
        float4 bb = *(const float4*)(bbs[s3] + mt*16 + g*4);
        uint2 o;
        o.x = packbf(acc[mt][0]+bb.x, acc[mt][1]+bb.y);
        o.y = packbf(acc[mt][2]+bb.z, acc[mt][3]+bb.w);
        *(uint2*)(op + mt*8 + g*2) = o;
      }
    }
  }
}

// ---------------- K2: fused edge pass (atomic-free) ----------------
__global__ __launch_bounds__(256)
void k_edge(const float* __restrict__ ein,
            const float* __restrict__ l1eg, const float* __restrict__ l1eb,
            const u16* __restrict__ pWg, const float* __restrict__ bg,
            const u16* __restrict__ pWe, const float* __restrict__ be,
            const u16* __restrict__ pWoe, const float* __restrict__ boe,
            const int* __restrict__ eidx,
            const u32* __restrict__ qv, const u32* __restrict__ kv, const u32* __restrict__ vv,
            u32* __restrict__ gvp, float* __restrict__ escp,
            float* __restrict__ eout)
{
  __shared__ u32 tile[64*64];
  int t = threadIdx.x;
  long base = (long)blockIdx.x * 64;
  stage_ln(ein, base, NE, l1eg, l1eb, tile, t);
  __syncthreads();
  int w = t>>6, l = t&63, g = l>>4;
  int row = w*16 + (l&15);
  long edge = base + row;
  int s_ = eidx[edge], d_ = eidx[NE + edge];
  const u32* qrow = qv + (size_t)d_*64;
  const u32* krow = kv + (size_t)s_*64;
  const u32* vrow = vv + (size_t)s_*64;

  f32x4 acc[8], gate[8];
  // gate = sigmoid(LN(e)@Wg + bg)
  #pragma unroll
  for(int mt=0;mt<8;++mt) acc[mt] = (f32x4){0.f,0.f,0.f,0.f};
  gemmT8(pWg, 8, 0, tile, row, l, acc);
  #pragma unroll
  for(int mt=0;mt<8;++mt){
    float4 bb = *(const float4*)(bg + mt*16 + g*4);
    gate[mt][0] = 1.f/(1.f+__expf(-(acc[mt][0]+bb.x)));
    gate[mt][1] = 1.f/(1.f+__expf(-(acc[mt][1]+bb.y)));
    gate[mt][2] = 1.f/(1.f+__expf(-(acc[mt][2]+bb.z)));
    gate[mt][3] = 1.f/(1.f+__expf(-(acc[mt][3]+bb.w)));
  }
  // s_elt = LN(e)@We + be + q[dst]*k[src]; scores -> esc
  #pragma unroll
  for(int mt=0;mt<8;++mt) acc[mt] = (f32x4){0.f,0.f,0.f,0.f};
  gemmT8(pWe, 8, 0, tile, row, l, acc);
  float esc[8];
  #pragma unroll
  for(int mt=0;mt<8;++mt){
    float4 bb = *(const float4*)(be + mt*16 + g*4);
    uint2 qw = *(const uint2*)(qrow + mt*8 + g*2);
    uint2 kw = *(const uint2*)(krow + mt*8 + g*2);
    acc[mt][0] += bb.x + bflo(qw.x)*bflo(kw.x);
    acc[mt][1] += bb.y + bfhi(qw.x)*bfhi(kw.x);
    acc[mt][2] += bb.z + bflo(qw.y)*bflo(kw.y);
    acc[mt][3] += bb.w + bfhi(qw.y)*bfhi(kw.y);
    float ps = acc[mt][0]+acc[mt][1]+acc[mt][2]+acc[mt][3];
    ps += __shfl_xor(ps, 16);
    ps += __shfl_xor(ps, 32);                  // sum over all 16 feats of head mt
    float sc = fminf(fmaxf(ps*0.25f, -5.f), 5.f);
    esc[mt] = __expf(sc);                      // clipped => no max-subtract needed
  }
  // store esc [E][8] f32 (one lane per edge)
  if (g==0){
    float4 e0 = {esc[0],esc[1],esc[2],esc[3]};
    float4 e1 = {esc[4],esc[5],esc[6],esc[7]};
    *(float4*)(escp + (size_t)edge*8)     = e0;
    *(float4*)(escp + (size_t)edge*8 + 4) = e1;
  }
  // store gv = gate (x) v[src]  (bf16 [E][128])
  #pragma unroll
  for(int mt=0;mt<8;++mt){
    uint2 vw = *(const uint2*)(vrow + mt*8 + g*2);
    uint2 o;
    o.x = packbf(gate[mt][0]*bflo(vw.x), gate[mt][1]*bfhi(vw.x));
    o.y = packbf(gate[mt][2]*bflo(vw.y), gate[mt][3]*bfhi(vw.y));
    *(uint2*)(gvp + (size_t)edge*64 + mt*8 + g*2) = o;
  }
  __syncthreads();                 // all waves done reading LN tile
  // write s_elt (bf16) into tile (B-layout for Woe GEMM)
  #pragma unroll
  for(int mt=0;mt<8;++mt){
    uint2 o;
    o.x = packbf(acc[mt][0], acc[mt][1]);
    o.y = packbf(acc[mt][2], acc[mt][3]);
    *(uint2*)&tile[swz64(row, mt*8 + g*2)] = o;
  }
  __syncthreads();
  // e_out = e_in + s_elt@Woe + boe
  f32x4 oacc[8];
  #pragma unroll
  for(int mt=0;mt<8;++mt) oacc[mt] = (f32x4){0.f,0.f,0.f,0.f};
  gemmT8(pWoe, 8, 0, tile, row, l, oacc);
  #pragma unroll
  for(int mt=0;mt<8;++mt){
    float4 bb = *(const float4*)(boe + mt*16 + g*4);
    float4 er = *(const float4*)(ein + edge*128 + mt*16 + g*4);
    float4 o;
    o.x = er.x + oacc[mt][0] + bb.x;
    o.y = er.y + oacc[mt][1] + bb.y;
    o.z = er.z + oacc[mt][2] + bb.z;
    o.w = er.w + oacc[mt][3] + bb.w;
    *(float4*)(eout + edge*128 + mt*16 + g*4) = o;
  }
}

// ---------------- K2b: per-node aggregation over CSR (no atomics) ----------------
__global__ __launch_bounds__(256)
void k_agg(const u32* __restrict__ gvp, const float* __restrict__ escp,
           const int* __restrict__ elist, const int* __restrict__ starts,
           const int* __restrict__ ends, float* __restrict__ xattn)
{
  int w = threadIdx.x>>6, l = threadIdx.x&63;
  long n = (long)blockIdx.x*4 + w;
  if (n >= NN) return;
  int h = l>>3;                       // head for feats 2l,2l+1
  int s = starts[n], e = ends[n];
  float s0=0.f, s1=0.f, den=0.f;
  for (int i=s;i<e;++i){
    int ed = elist[i];
    u32 gvw = gvp[(size_t)ed*64 + l];
    float a = escp[(size_t)ed*8 + h];
    s0 += a*bflo(gvw);
    s1 += a*bfhi(gvw);
    den += a;
  }
  float inv = den>0.f ? 1.f/den : 0.f;  // zero in-degree -> 0 (segment_sum semantics)
  float2 o; o.x = s0*inv; o.y = s1*inv;
  *(float2*)(xattn + n*128 + 2*l) = o;
}

// ---------------- K3: node epilogue: Wo, LN2, FFN ----------------
__global__ __launch_bounds__(256)
void k_out(const float* __restrict__ xin,
           const float* __restrict__ accN,
           const u16* __restrict__ pWo, const float* __restrict__ bo,
           const float* __restrict__ l2g, const float* __restrict__ l2b,
           const u16* __restrict__ pW1, const float* __restrict__ b1p,
           const u16* __restrict__ pW2, const float* __restrict__ b2p,
           float* __restrict__ xout)
{
  __shared__ u32 tile[64*64];
  __shared__ u32 htile[64*128];
  int t = threadIdx.x;
  long base = (long)blockIdx.x * 64;
  // stage normalized attention output -> bf16 tile
  {
    int row = t>>2, sub = t&3;
    long node = base + row;
    bool valid = node < NN;
    const float* p = accN + node*128 + sub*32;
    #pragma unroll
    for(int m4=0;m4<4;++m4){
      float4 xa = valid ? *(const float4*)(p + 8*m4)     : make_float4(0.f,0.f,0.f,0.f);
      float4 xb = valid ? *(const float4*)(p + 8*m4 + 4) : make_float4(0.f,0.f,0.f,0.f);
      uint4 wv;
      wv.x = packbf(xa.x, xa.y);
      wv.y = packbf(xa.z, xa.w);
      wv.z = packbf(xb.x, xb.y);
      wv.w = packbf(xb.z, xb.w);
      *(uint4*)&tile[swz64(row, sub*16 + m4*4)] = wv;
    }
  }
  __syncthreads();
  int w = t>>6, l = t&63, g = l>>4;
  int row = w*16 + (l&15);
  long node = base + row;
  bool valid = node < NN;

  // Wo GEMM; xmid = x_in + out@Wo + bo
  f32x4 acc[8], xm[8];
  #pragma unroll
  for(int mt=0;mt<8;++mt) acc[mt] = (f32x4){0.f,0.f,0.f,0.f};
  gemmT8(pWo, 8, 0, tile, row, l, acc);
  #pragma unroll
  for(int mt=0;mt<8;++mt){
    float4 bb = *(const float4*)(bo + mt*16 + g*4);
    float4 xr = valid ? *(const float4*)(xin + node*128 + mt*16 + g*4) : make_float4(0.f,0.f,0.f,0.f);
    xm[mt][0] = xr.x + acc[mt][0] + bb.x;
    xm[mt][1] = xr.y + acc[mt][1] + bb.y;
    xm[mt][2] = xr.z + acc[mt][2] + bb.z;
    xm[mt][3] = xr.w + acc[mt][3] + bb.w;
  }
  // LN2 in-register
  float s=0.f, s2=0.f;
  #pragma unroll
  for(int mt=0;mt<8;++mt){
    s  += xm[mt][0]+xm[mt][1]+xm[mt][2]+xm[mt][3];
    s2 += xm[mt][0]*xm[mt][0]+xm[mt][1]*xm[mt][1]+xm[mt][2]*xm[mt][2]+xm[mt][3]*xm[mt][3];
  }
  s  += __shfl_xor(s,16);  s  += __shfl_xor(s,32);
  s2 += __shfl_xor(s2,16); s2 += __shfl_xor(s2,32);
  float mu  = s*(1.f/128.f);
  float var = fmaxf(s2*(1.f/128.f) - mu*mu, 0.f);
  float rs  = rsqrtf(var + 1e-5f);
  __syncthreads();              // done reading tile (Wo B-frags)
  #pragma unroll
  for(int mt=0;mt<8;++mt){
    float4 gg = *(const float4*)(l2g + mt*16 + g*4);
    float4 bb = *(const float4*)(l2b + mt*16 + g*4);
    float h0 = (xm[mt][0]-mu)*rs*gg.x + bb.x;
    float h1 = (xm[mt][1]-mu)*rs*gg.y + bb.y;
    float h2 = (xm[mt][2]-mu)*rs*gg.z + bb.z;
    float h3 = (xm[mt][3]-mu)*rs*gg.w + bb.w;
    uint2 o; o.x = packbf(h0,h1); o.y = packbf(h2,h3);
    *(uint2*)&tile[swz64(row, mt*8 + g*2)] = o;
  }
  __syncthreads();
  // FFN layer 1 (256 outs in two halves), relu -> htile
  #pragma unroll
  for(int half=0; half<2; ++half){
    f32x4 dh[8];
    #pragma unroll
    for(int mt=0;mt<8;++mt) dh[mt] = (f32x4){0.f,0.f,0.f,0.f};
    gemmT8(pW1, 16, half*8, tile, row, l, dh);
    #pragma unroll
    for(int mt=0;mt<8;++mt){
      int feat = half*128 + mt*16 + g*4;
      float4 bb = *(const float4*)(b1p + feat);
      float h0 = fmaxf(dh[mt][0]+bb.x, 0.f);
      float h1 = fmaxf(dh[mt][1]+bb.y, 0.f);
      float h2 = fmaxf(dh[mt][2]+bb.z, 0.f);
      float h3 = fmaxf(dh[mt][3]+bb.w, 0.f);
      uint2 o; o.x = packbf(h0,h1); o.y = packbf(h2,h3);
      *(uint2*)&htile[swz128(row, feat>>1)] = o;
    }
  }
  __syncthreads();
  // FFN layer 2 (K=256) + residual
  f32x4 oacc[8];
  #pragma unroll
  for(int mt=0;mt<8;++mt) oacc[mt] = (f32x4){0.f,0.f,0.f,0.f};
  gemmT8_k256(pW2, htile, row, l, oacc);
  if (valid){
    #pragma unroll
    for(int mt=0;mt<8;++mt){
      float4 bb = *(const float4*)(b2p + mt*16 + g*4);
      float4 o;
      o.x = xm[mt][0] + oacc[mt][0] + bb.x;
      o.y = xm[mt][1] + oacc[mt][1] + bb.y;
      o.z = xm[mt][2] + oacc[mt][2] + bb.z;
      o.w = xm[mt][3] + oacc[mt][3] + bb.w;
      *(float4*)(xout + node*128 + mt*16 + g*4) = o;
    }
  }
}

extern "C" void kernel_launch(void* const* d_in, const int* in_sizes, int n_in,
                              void* d_out, int out_size, void* d_ws, size_t ws_size,
                              hipStream_t stream) {
  (void)in_sizes; (void)n_in; (void)out_size; (void)ws_size;
  const float* xin = (const float*)d_in[0];
  const float* ein = (const float*)d_in[1];
  const float* Wq = (const float*)d_in[2];  const float* bq = (const float*)d_in[3];
  const float* Wk = (const float*)d_in[4];  const float* bk = (const float*)d_in[5];
  const float* Wv = (const float*)d_in[6];  const float* bv = (const float*)d_in[7];
  const float* We = (const float*)d_in[8];  const float* be = (const float*)d_in[9];
  const float* Wg = (const float*)d_in[10]; const float* bg = (const float*)d_in[11];
  const float* Wo = (const float*)d_in[12]; const float* bo = (const float*)d_in[13];
  const float* Woe= (const float*)d_in[14]; const float* boe= (const float*)d_in[15];
  const float* l1g= (const float*)d_in[16]; const float* l1b= (const float*)d_in[17];
  const float* l1eg=(const float*)d_in[18]; const float* l1eb=(const float*)d_in[19];
  const float* l2g= (const float*)d_in[20]; const float* l2b= (const float*)d_in[21];
  const float* W1 = (const float*)d_in[22]; const float* b1 = (const float*)d_in[23];
  const float* W2 = (const float*)d_in[24]; const float* b2 = (const float*)d_in[25];
  const int* eidx = (const int*)d_in[26];

  float* xout = (float*)d_out;
  float* eout = xout + (size_t)NN*128;
  float* xattn = xout;                       // x_out region holds normalized attn out

  // ws: esc [NE*8 f32] | gv [NE*64 u32] | qv,kv,vv [NN*64 u32] | deg,starts,cursor [NN] | elist [NE] | packed W
  float* escp = (float*)d_ws;
  u32* gvp = (u32*)(escp + (size_t)NE*8);
  u32* qv = gvp + (size_t)NE*64;
  u32* kv = qv + (size_t)NN*64;
  u32* vv = kv + (size_t)NN*64;
  int* deg = (int*)(vv + (size_t)NN*64);
  int* starts = deg + NN;
  int* cursor = starts + NN;
  int* elist = cursor + NN;
  u16* pw  = (u16*)(elist + NE);
  u16* pWq = pw;            u16* pWk = pWq + 16384;  u16* pWv = pWk + 16384;
  u16* pWe = pWv + 16384;   u16* pWg = pWe + 16384;  u16* pWoe= pWg + 16384;
  u16* pWo = pWoe + 16384;  u16* pW1 = pWo + 16384;  u16* pW2 = pW1 + 32768;

  k_pack<<<64, 256, 0, stream>>>(Wq,  pWq, 128, 128);
  k_pack<<<64, 256, 0, stream>>>(Wk,  pWk, 128, 128);
  k_pack<<<64, 256, 0, stream>>>(Wv,  pWv, 128, 128);
  k_pack<<<64, 256, 0, stream>>>(We,  pWe, 128, 128);
  k_pack<<<64, 256, 0, stream>>>(Wg,  pWg, 128, 128);
  k_pack<<<64, 256, 0, stream>>>(Woe, pWoe,128, 128);
  k_pack<<<64, 256, 0, stream>>>(Wo,  pWo, 128, 128);
  k_pack<<<128,256, 0, stream>>>(W1,  pW1, 128, 256);
  k_pack<<<128,256, 0, stream>>>(W2,  pW2, 256, 128);

  // CSR build
  hipMemsetAsync(deg, 0, NN*sizeof(int), stream);
  k_deg<<<(NE+255)/256, 256, 0, stream>>>(eidx, deg);
  k_scan<<<1, 1024, 0, stream>>>(deg, starts, cursor);
  k_scatter<<<(NE+255)/256, 256, 0, stream>>>(eidx, cursor, elist);

  k_qkv<<<(NN+63)/64, 256, 0, stream>>>(xin, l1g, l1b, pWq, bq, pWk, bk, pWv, bv, qv, kv, vv);
  k_edge<<<NE/64, 256, 0, stream>>>(ein, l1eg, l1eb, pWg, bg, pWe, be, pWoe, boe,
                                    eidx, qv, kv, vv, gvp, escp, eout);
  k_agg<<<(NN+3)/4, 256, 0, stream>>>(gvp, escp, elist, starts, cursor, xattn);
  k_out<<<(NN+63)/64, 256, 0, stream>>>(xin, xattn, pWo, bo, l2g, l2b,
                                        pW1, b1, pW2, b2, xout);
}